// Round 3
// baseline (4904.422 us; speedup 1.0000x reference)
//
#include <hip/hip_runtime.h>
#include <math.h>

namespace {

typedef __bf16 bf16_t;
typedef bf16_t bf16x8 __attribute__((ext_vector_type(8)));
typedef float floatx4 __attribute__((ext_vector_type(4)));

constexpr int kN = 1024;      // tokens
constexpr int kM = 64;        // multiplicity
constexpr int kP = 64;        // PE dim
constexpr int kD = 256;       // 4*M
constexpr float kEps = 1e-5f;
constexpr int kFN = 1024;     // FFT length

__device__ __forceinline__ float sigmoidf(float v) { return 1.0f / (1.0f + expf(-v)); }

__device__ __forceinline__ floatx4 mfma16(bf16x8 a, bf16x8 b, floatx4 c) {
  return __builtin_amdgcn_mfma_f32_16x16x32_bf16(a, b, c, 0, 0, 0);
}

// 3-term split product: acc += (ah+al)*(bh+bl) dropping al*bl
__device__ __forceinline__ void fma3(floatx4& acc, bf16x8 ah, bf16x8 al,
                                     bf16x8 bh, bf16x8 bl) {
  acc = mfma16(ah, bh, acc);
  acc = mfma16(ah, bl, acc);
  acc = mfma16(al, bh, acc);
}

// load 8 contiguous fp32, split into hi/lo bf16 fragments
__device__ __forceinline__ void load_split8(const float* p, bf16x8& hi, bf16x8& lo) {
  const float4 u = *(const float4*)p;
  const float4 v = *(const float4*)(p + 4);
  const float a[8] = {u.x, u.y, u.z, u.w, v.x, v.y, v.z, v.w};
#pragma unroll
  for (int i = 0; i < 8; ++i) {
    const bf16_t h_ = (bf16_t)a[i];
    hi[i] = h_;
    lo[i] = (bf16_t)(a[i] - (float)h_);
  }
}

// ---------------------------------------------------------------- init
__global__ void k_zero(float* p) { p[threadIdx.x] = 0.0f; }

// s0[n, m] = sum_p (pe[n,p] + tok_emb[tt[n],p]) * Wf[p,m]
__global__ void k_s0(const float* __restrict__ tok_emb, const float* __restrict__ Wf,
                     float* __restrict__ s0) {
  __shared__ float f[kP];
  const int n = blockIdx.x;
  const int t = threadIdx.x;                       // 64 threads
  const int tt = (n == kN - 1) ? 2 : (n & 1);
  const int j = t >> 1;
  const float cexp = (float)(-9.210340371976184 / 64.0);   // -ln(10000)/P
  const float divj = expf((float)(2 * j) * cexp);
  const float ang = (float)n * divj;
  const float pe = (t & 1) ? cosf(ang) : sinf(ang);
  f[t] = pe + tok_emb[tt * kP + t];
  __syncthreads();
  float acc = 0.0f;
#pragma unroll 8
  for (int p = 0; p < kP; ++p) acc = fmaf(f[p], Wf[p * kM + t], acc);
  s0[n * kM + t] = acc;
}

// h[r, m, 0..3] = (s0[n,m], x[r]*wv[m])
__global__ void k_h0(const float* __restrict__ x, const float* __restrict__ wv,
                     const float* __restrict__ s0, float* __restrict__ h) {
  const int idx = blockIdx.x * 256 + threadIdx.x;  // r*64 + m
  const int r = idx >> 6;
  const int m = idx & 63;
  const int n = r & (kN - 1);
  const float w = wv[m];
  float4 o;
  o.x = s0[n * kM + m];
  o.y = x[r * 3 + 0] * w;
  o.z = x[r * 3 + 1] * w;
  o.w = x[r * 3 + 2] * w;
  ((float4*)h)[idx] = o;
}

// ---------------------------------------------------------------- weight prep (hi/lo planes)
__global__ void k_wqkv(const float* __restrict__ Wq, const float* __restrict__ Wk,
                       const float* __restrict__ Wv, int H,
                       bf16_t* __restrict__ Wq_hi, bf16_t* __restrict__ Wq_lo,
                       bf16_t* __restrict__ Wk_hi, bf16_t* __restrict__ Wk_lo,
                       bf16_t* __restrict__ Wv_hi, bf16_t* __restrict__ Wv_lo) {
  const int c = blockIdx.x;    // 0..383
  const int k = threadIdx.x;   // 0..255
  const bool ok = c < H;
  const float wq = ok ? Wq[k * H + c] : 0.f;
  const float wk = ok ? Wk[k * H + c] : 0.f;
  const float wv = ok ? Wv[k * H + c] : 0.f;
  const bf16_t qh = (bf16_t)wq, kh = (bf16_t)wk, vh = (bf16_t)wv;
  Wq_hi[c * 256 + k] = qh; Wq_lo[c * 256 + k] = (bf16_t)(wq - (float)qh);
  Wk_hi[c * 256 + k] = kh; Wk_lo[c * 256 + k] = (bf16_t)(wk - (float)kh);
  Wv_hi[c * 256 + k] = vh; Wv_lo[c * 256 + k] = (bf16_t)(wv - (float)vh);
}

__global__ void k_wo(const float* __restrict__ Wo, int H,
                     bf16_t* __restrict__ Wo_hi, bf16_t* __restrict__ Wo_lo) {
  const int d = blockIdx.x;    // 0..255
  const int c = threadIdx.x;   // 0..383
  const float w = (c < H) ? Wo[c * 256 + d] : 0.f;
  const bf16_t hi = (bf16_t)w;
  Wo_hi[d * 384 + c] = hi;
  Wo_lo[d * 384 + c] = (bf16_t)(w - (float)hi);
}

// block-diagonal expanded reg_linear weight, transposed: Bt[col][row]
__global__ void k_bt(const float* __restrict__ W0, const float* __restrict__ W1,
                     bf16_t* __restrict__ Bt_hi, bf16_t* __restrict__ Bt_lo) {
  const int col = blockIdx.x, row = threadIdx.x;
  const int k = col >> 2, ck = col & 3, m = row >> 2, cm = row & 3;
  float v = 0.f;
  if (cm == ck) v = (ck == 0 ? W0 : W1)[m * 64 + k];
  const bf16_t hi = (bf16_t)v;
  Bt_hi[col * 256 + row] = hi;
  Bt_lo[col * 256 + row] = (bf16_t)(v - (float)hi);
}

// ---------------------------------------------------------------- FFT (radix-2, no bit-reversal)
__device__ void fft_build_tw(float2* tw) {
  for (int j = threadIdx.x; j < kFN / 2; j += 256) {
    float s, c;
    sincosf(-6.283185307179586f * (float)j / (float)kFN, &s, &c);
    tw[j].x = c; tw[j].y = s;
  }
}

// forward DIF: natural in -> bit-reversed out
__device__ void fft_dif(float2* z, const float2* tw) {
  for (int span = kFN / 2; span >= 1; span >>= 1) {
    const int tm = (kFN / 2) / span;
    __syncthreads();
#pragma unroll
    for (int it = 0; it < 2; ++it) {
      const int p = threadIdx.x + it * 256;
      const int k = p & (span - 1);
      const int i = ((p & ~(span - 1)) << 1) | k;
      const float2 u = z[i];
      const float2 v = z[i + span];
      const float2 w = tw[k * tm];
      float2 sum, d, o;
      sum.x = u.x + v.x; sum.y = u.y + v.y;
      d.x = u.x - v.x;   d.y = u.y - v.y;
      o.x = d.x * w.x - d.y * w.y;
      o.y = d.x * w.y + d.y * w.x;
      z[i] = sum;
      z[i + span] = o;
    }
  }
}

// inverse DIT: bit-reversed in -> natural out (caller scales by 1/N)
__device__ void fft_dit_inv(float2* z, const float2* tw) {
  for (int span = 1; span <= kFN / 2; span <<= 1) {
    const int tm = (kFN / 2) / span;
    __syncthreads();
#pragma unroll
    for (int it = 0; it < 2; ++it) {
      const int p = threadIdx.x + it * 256;
      const int k = p & (span - 1);
      const int i = ((p & ~(span - 1)) << 1) | k;
      const float2 w = tw[k * tm];         // conj used below
      const float2 v = z[i + span];
      float2 tv, a, bq;
      tv.x = v.x * w.x + v.y * w.y;
      tv.y = v.y * w.x - v.x * w.y;
      const float2 u = z[i];
      a.x = u.x + tv.x;  a.y = u.y + tv.y;
      bq.x = u.x - tv.x; bq.y = u.y - tv.y;
      z[i] = a;
      z[i + span] = bq;
    }
  }
}

// filter spectrum, stored in DIF (bit-reversed) order; one block per channel
__global__ __launch_bounds__(256) void k_kf(const float* __restrict__ filt, int H,
                                            float2* __restrict__ kf) {
  __shared__ float2 z[kFN];
  __shared__ float2 tw[kFN / 2];
  const int c = blockIdx.x;
  fft_build_tw(tw);
  for (int n = threadIdx.x; n < kFN; n += 256) {
    z[n].x = filt[n * H + c];
    z[n].y = 0.0f;
  }
  fft_dif(z, tw);
  __syncthreads();
  for (int j = threadIdx.x; j < kFN; j += 256) kf[c * kFN + j] = z[j];
}

// circular conv in-place on kv_t rows; one block per (b, c)
__global__ __launch_bounds__(256) void k_conv(float* kvt, const float2* __restrict__ kf, int H) {
  __shared__ float2 z[kFN];
  __shared__ float2 tw[kFN / 2];
  const int row = blockIdx.x;              // b*H + c
  const int c = row % H;
  float* sig = kvt + (size_t)row * kFN;
  fft_build_tw(tw);
  for (int n = threadIdx.x; n < kFN; n += 256) {
    z[n].x = sig[n];
    z[n].y = 0.0f;
  }
  fft_dif(z, tw);
  __syncthreads();
  for (int j = threadIdx.x; j < kFN; j += 256) {
    const float2 a = z[j];
    const float2 b = kf[c * kFN + j];
    float2 o;
    o.x = a.x * b.x - a.y * b.y;
    o.y = a.x * b.y + a.y * b.x;
    z[j] = o;
  }
  fft_dit_inv(z, tw);
  __syncthreads();
  const float s = 1.0f / (float)kFN;
  for (int n = threadIdx.x; n < kFN; n += 256) sig[n] = z[n].x * s;
}

// ---------------------------------------------------------------- GEMM 1 (split MFMA): q/k/v
// Aq[row][c] fp32 (stride S) = h@Wq ; kvt[b*H+c][n] fp32 = (h@Wk)*(h@Wv)
__global__ __launch_bounds__(256) void k_qkv(const float* __restrict__ h,
    const bf16_t* __restrict__ Wq_hi, const bf16_t* __restrict__ Wq_lo,
    const bf16_t* __restrict__ Wk_hi, const bf16_t* __restrict__ Wk_lo,
    const bf16_t* __restrict__ Wv_hi, const bf16_t* __restrict__ Wv_lo,
    int H, int S, float* __restrict__ Aq, float* __restrict__ kvt) {
  const int t = threadIdx.x;
  const int lane = t & 63, wave = t >> 6;
  const int l15 = lane & 15, quad = lane >> 4;
  const int c0 = blockIdx.x * 64;          // output channels (fast dim -> L2 reuse of h)
  const int r0 = blockIdx.y * 64;          // flattened token rows
  const int wr = (wave & 1) * 32, wc = (wave >> 1) * 32;
  floatx4 aq[2][2] = {}, ak_[2][2] = {}, av_[2][2] = {};
  const float* Ap = h + (size_t)(r0 + wr + l15) * 256 + quad * 8;
  const size_t boff = (size_t)(c0 + wc + l15) * 256 + quad * 8;
  for (int kk = 0; kk < 256; kk += 32) {
    bf16x8 ah0, al0, ah1, al1;
    load_split8(Ap + kk, ah0, al0);
    load_split8(Ap + 16 * 256 + kk, ah1, al1);
    {
      const bf16x8 bh0 = *(const bf16x8*)(Wq_hi + boff + kk);
      const bf16x8 bh1 = *(const bf16x8*)(Wq_hi + boff + 16 * 256 + kk);
      const bf16x8 bl0 = *(const bf16x8*)(Wq_lo + boff + kk);
      const bf16x8 bl1 = *(const bf16x8*)(Wq_lo + boff + 16 * 256 + kk);
      fma3(aq[0][0], ah0, al0, bh0, bl0); fma3(aq[0][1], ah0, al0, bh1, bl1);
      fma3(aq[1][0], ah1, al1, bh0, bl0); fma3(aq[1][1], ah1, al1, bh1, bl1);
    }
    {
      const bf16x8 bh0 = *(const bf16x8*)(Wk_hi + boff + kk);
      const bf16x8 bh1 = *(const bf16x8*)(Wk_hi + boff + 16 * 256 + kk);
      const bf16x8 bl0 = *(const bf16x8*)(Wk_lo + boff + kk);
      const bf16x8 bl1 = *(const bf16x8*)(Wk_lo + boff + 16 * 256 + kk);
      fma3(ak_[0][0], ah0, al0, bh0, bl0); fma3(ak_[0][1], ah0, al0, bh1, bl1);
      fma3(ak_[1][0], ah1, al1, bh0, bl0); fma3(ak_[1][1], ah1, al1, bh1, bl1);
    }
    {
      const bf16x8 bh0 = *(const bf16x8*)(Wv_hi + boff + kk);
      const bf16x8 bh1 = *(const bf16x8*)(Wv_hi + boff + 16 * 256 + kk);
      const bf16x8 bl0 = *(const bf16x8*)(Wv_lo + boff + kk);
      const bf16x8 bl1 = *(const bf16x8*)(Wv_lo + boff + 16 * 256 + kk);
      fma3(av_[0][0], ah0, al0, bh0, bl0); fma3(av_[0][1], ah0, al0, bh1, bl1);
      fma3(av_[1][0], ah1, al1, bh0, bl0); fma3(av_[1][1], ah1, al1, bh1, bl1);
    }
  }
  const int b = r0 >> 10;
  const int n0 = r0 & 1023;
#pragma unroll
  for (int j = 0; j < 2; ++j) {
    const int c = c0 + wc + j * 16 + l15;
    if (c < H) {
      // q -> Aq[row][c] (C/D layout: lane = one column, rows quad*4+r (+16i))
      float* qb = Aq + (size_t)(r0 + wr + quad * 4) * S + c;
#pragma unroll
      for (int i = 0; i < 2; ++i)
#pragma unroll
        for (int r = 0; r < 4; ++r)
          qb[(size_t)(i * 16 + r) * S] = aq[i][j][r];
      // kv -> kvt[b*H+c][n], float4 along n
      float* kb = kvt + (((size_t)(b * H + c)) << 10) + n0 + wr + quad * 4;
#pragma unroll
      for (int i = 0; i < 2; ++i) {
        float4 p;
        p.x = ak_[i][j][0] * av_[i][j][0];
        p.y = ak_[i][j][1] * av_[i][j][1];
        p.z = ak_[i][j][2] * av_[i][j][2];
        p.w = ak_[i][j][3] * av_[i][j][3];
        *(float4*)(kb + i * 16) = p;
      }
    }
  }
}

// ---------------------------------------------------------------- Aq *= conv^T (fp32 in-place)
__global__ __launch_bounds__(256) void k_tq(const float* __restrict__ kvt,
                                            float* __restrict__ Aq, int H, int S) {
  __shared__ float cs[64 * 68];
  const int t = threadIdx.x;
  const int n0 = blockIdx.x * 64;
  const int c0 = blockIdx.y * 64;
  const int b  = blockIdx.z;
  const int cl = t >> 2, q4 = t & 3;
  {
    const int c = c0 + cl;
    if (c < H) {
      const float* src = kvt + (((size_t)(b * H + c)) << 10) + n0 + q4 * 16;
#pragma unroll
      for (int u = 0; u < 4; ++u) {
        const float4 v = *(const float4*)(src + u * 4);
        cs[cl * 68 + q4 * 16 + u * 4 + 0] = v.x;
        cs[cl * 68 + q4 * 16 + u * 4 + 1] = v.y;
        cs[cl * 68 + q4 * 16 + u * 4 + 2] = v.z;
        cs[cl * 68 + q4 * 16 + u * 4 + 3] = v.w;
      }
    }
  }
  __syncthreads();
  {
    const int nl = t >> 2;
    const size_t rbase = (size_t)((b << 10) + n0 + nl) * S;
#pragma unroll
    for (int u4 = 0; u4 < 4; ++u4) {
      const int cb = c0 + q4 * 16 + u4 * 4;
      if (cb < H) {            // H multiple of 4
        float4 qv = *(const float4*)(Aq + rbase + cb);
        const int clb = q4 * 16 + u4 * 4;
        qv.x *= cs[(clb + 0) * 68 + nl];
        qv.y *= cs[(clb + 1) * 68 + nl];
        qv.z *= cs[(clb + 2) * 68 + nl];
        qv.w *= cs[(clb + 3) * 68 + nl];
        *(float4*)(Aq + rbase + cb) = qv;
      }
    }
  }
}

// ---------------------------------------------------------------- GEMM 2 (split MFMA): h += Aq @ Wo
__global__ __launch_bounds__(256) void k_mix(const float* __restrict__ Aq, int S, int Kpad,
    const bf16_t* __restrict__ Wo_hi, const bf16_t* __restrict__ Wo_lo,
    float* __restrict__ h) {
  __shared__ float sm[64 * 68];
  const int t = threadIdx.x;
  const int lane = t & 63, wave = t >> 6;
  const int l15 = lane & 15, quad = lane >> 4;
  const int d0 = blockIdx.x * 64, r0 = blockIdx.y * 64;
  const int wr = (wave & 1) * 32, wc = (wave >> 1) * 32;
  floatx4 acc[2][2] = {};
  const float* Ap = Aq + (size_t)(r0 + wr + l15) * S + quad * 8;
  const size_t boff = (size_t)(d0 + wc + l15) * 384 + quad * 8;
  for (int kk = 0; kk < Kpad; kk += 32) {
    bf16x8 ah0, al0, ah1, al1;
    load_split8(Ap + kk, ah0, al0);                 // tail cols >=H: finite garbage * 0-weight
    load_split8(Ap + (size_t)16 * S + kk, ah1, al1);
    const bf16x8 bh0 = *(const bf16x8*)(Wo_hi + boff + kk);
    const bf16x8 bh1 = *(const bf16x8*)(Wo_hi + boff + 16 * 384 + kk);
    const bf16x8 bl0 = *(const bf16x8*)(Wo_lo + boff + kk);
    const bf16x8 bl1 = *(const bf16x8*)(Wo_lo + boff + 16 * 384 + kk);
    fma3(acc[0][0], ah0, al0, bh0, bl0); fma3(acc[0][1], ah0, al0, bh1, bl1);
    fma3(acc[1][0], ah1, al1, bh0, bl0); fma3(acc[1][1], ah1, al1, bh1, bl1);
  }
#pragma unroll
  for (int i = 0; i < 2; ++i)
#pragma unroll
    for (int j = 0; j < 2; ++j)
#pragma unroll
      for (int r = 0; r < 4; ++r)
        sm[(wr + i * 16 + quad * 4 + r) * 68 + wc + j * 16 + l15] = acc[i][j][r];
  __syncthreads();
  const int nl = t >> 2, q4 = t & 3;
  const size_t gi = (size_t)(r0 + nl) * 256 + d0 + q4 * 16;
#pragma unroll
  for (int u = 0; u < 4; ++u) {
    float4 hv = *(const float4*)(h + gi + u * 4);
    hv.x += sm[nl * 68 + q4 * 16 + u * 4 + 0];
    hv.y += sm[nl * 68 + q4 * 16 + u * 4 + 1];
    hv.z += sm[nl * 68 + q4 * 16 + u * 4 + 2];
    hv.w += sm[nl * 68 + q4 * 16 + u * 4 + 3];
    *(float4*)(h + gi + u * 4) = hv;
  }
}

// ---------------------------------------------------------------- GEMM 3 (split MFMA): reg_linear + BN stats
__global__ __launch_bounds__(256) void k_reg(const float* __restrict__ h,
    const bf16_t* __restrict__ Bt_hi, const bf16_t* __restrict__ Bt_lo,
    float* __restrict__ y, float* __restrict__ st) {
  __shared__ float sm[64 * 68];
  __shared__ float red[128];
  const int t = threadIdx.x;
  const int lane = t & 63, wave = t >> 6;
  const int l15 = lane & 15, quad = lane >> 4;
  const int c0 = blockIdx.x * 64, r0 = blockIdx.y * 64;
  const int wr = (wave & 1) * 32, wc = (wave >> 1) * 32;
  floatx4 acc[2][2] = {};
  const float* Ap = h + (size_t)(r0 + wr + l15) * 256 + quad * 8;
  const size_t boff = (size_t)(c0 + wc + l15) * 256 + quad * 8;
  for (int kk = 0; kk < 256; kk += 32) {
    bf16x8 ah0, al0, ah1, al1;
    load_split8(Ap + kk, ah0, al0);
    load_split8(Ap + 16 * 256 + kk, ah1, al1);
    const bf16x8 bh0 = *(const bf16x8*)(Bt_hi + boff + kk);
    const bf16x8 bh1 = *(const bf16x8*)(Bt_hi + boff + 16 * 256 + kk);
    const bf16x8 bl0 = *(const bf16x8*)(Bt_lo + boff + kk);
    const bf16x8 bl1 = *(const bf16x8*)(Bt_lo + boff + 16 * 256 + kk);
    fma3(acc[0][0], ah0, al0, bh0, bl0); fma3(acc[0][1], ah0, al0, bh1, bl1);
    fma3(acc[1][0], ah1, al1, bh0, bl0); fma3(acc[1][1], ah1, al1, bh1, bl1);
  }
  // per-column sum of squares (lane holds one column per j)
#pragma unroll
  for (int j = 0; j < 2; ++j) {
    float s = 0.f;
#pragma unroll
    for (int i = 0; i < 2; ++i)
#pragma unroll
      for (int r = 0; r < 4; ++r)
        s = fmaf(acc[i][j][r], acc[i][j][r], s);
    s += __shfl_down(s, 32);
    s += __shfl_down(s, 16);
    if (lane < 16) red[wave * 32 + j * 16 + lane] = s;
  }
#pragma unroll
  for (int i = 0; i < 2; ++i)
#pragma unroll
    for (int j = 0; j < 2; ++j)
#pragma unroll
      for (int r = 0; r < 4; ++r)
        sm[(wr + i * 16 + quad * 4 + r) * 68 + wc + j * 16 + l15] = acc[i][j][r];
  __syncthreads();
  const int nl = t >> 2, q4 = t & 3;
  const size_t gi = (size_t)(r0 + nl) * 256 + c0 + q4 * 16;
#pragma unroll
  for (int u = 0; u < 4; ++u) {
    float4 yv;
    yv.x = sm[nl * 68 + q4 * 16 + u * 4 + 0];
    yv.y = sm[nl * 68 + q4 * 16 + u * 4 + 1];
    yv.z = sm[nl * 68 + q4 * 16 + u * 4 + 2];
    yv.w = sm[nl * 68 + q4 * 16 + u * 4 + 3];
    *(float4*)(y + gi + u * 4) = yv;
  }
  if (t < 64) {
    const int w0 = (t >= 32) ? 2 : 0;
    const float v = red[w0 * 32 + (t & 31)] + red[(w0 + 1) * 32 + (t & 31)];
    const int cg = c0 + t;
    atomicAdd(&st[((cg & 3) ? 64 : 0) + (cg >> 2)], v);
  }
}

// ---------------------------------------------------------------- BN + norm-activation + residual
__global__ void k_bnact(const float* __restrict__ y, const float* __restrict__ stats,
    const float* __restrict__ g0, const float* __restrict__ g1, float* __restrict__ h) {
  const int idx = blockIdx.x * 256 + threadIdx.x;  // r*64 + m
  const int m = idx & 63;
  const float inv0 = g0[m] / sqrtf(stats[m] * (1.0f / 65536.0f) + kEps);
  const float inv1 = g1[m] / sqrtf(stats[64 + m] * (1.0f / 65536.0f) + kEps);
  const float4 v = ((const float4*)y)[idx];
  const float s = v.x * inv0;
  const float vx = v.y * inv1, vy = v.z * inv1, vz = v.w * inv1;
  const float so = s * sigmoidf(fabsf(s));
  const float vn = sqrtf(fmaf(vx, vx, fmaf(vy, vy, vz * vz)) + kEps);
  const float gv = sigmoidf(vn);
  float4 hv = ((float4*)h)[idx];
  hv.x += so;
  hv.y += vx * gv; hv.z += vy * gv; hv.w += vz * gv;
  ((float4*)h)[idx] = hv;
}

// ---------------------------------------------------------------- mean-pool + einsum
__global__ __launch_bounds__(256) void k_pool(const float* __restrict__ h,
    const float* __restrict__ w_out, float* __restrict__ out) {
  __shared__ float r0s[256], r1s[256], r2s[256];
  const int b = blockIdx.x;
  const int t = threadIdx.x;
  float p0 = 0, p1 = 0, p2 = 0;
  for (int idx = t; idx < kN * kM; idx += 256) {
    const int m = idx & 63;
    const float4 v = ((const float4*)h)[(size_t)b * (kN * kM) + idx];
    const float w = w_out[m];
    p0 = fmaf(v.y, w, p0);
    p1 = fmaf(v.z, w, p1);
    p2 = fmaf(v.w, w, p2);
  }
  r0s[t] = p0; r1s[t] = p1; r2s[t] = p2;
  __syncthreads();
  for (int s = 128; s > 0; s >>= 1) {
    if (t < s) { r0s[t] += r0s[t + s]; r1s[t] += r1s[t + s]; r2s[t] += r2s[t + s]; }
    __syncthreads();
  }
  if (t == 0) {
    out[b * 3 + 0] = r0s[0] * (1.0f / kN);
    out[b * 3 + 1] = r1s[0] * (1.0f / kN);
    out[b * 3 + 2] = r2s[0] * (1.0f / kN);
  }
}

} // namespace

extern "C" void kernel_launch(void* const* d_in, const int* in_sizes, int n_in,
                              void* d_out, int out_size, void* d_ws, size_t ws_size,
                              hipStream_t stream) {
  const float* x       = (const float*)d_in[0];
  const float* tok_emb = (const float*)d_in[1];
  const float* Wf      = (const float*)d_in[2];
  const float* wv      = (const float*)d_in[3];
  const float* w_out   = (const float*)d_in[4];

  float* ws    = (float*)d_ws;
  float*  h    = ws;                                   // 16,777,216 fl
  float*  kvt  = ws + 16777216;                        // 23,592,960 fl
  float*  y    = kvt;                                  // alias (kvt dead when y live)
  float*  Aq   = kvt + 23592960;                       // 23,592,960 fl (65536 x 360 max)
  float*  s0   = Aq + 23592960;                        //     65,536 fl (also pads Aq tail reads)
  float*  kf   = s0 + 65536;                           //    737,280 fl
  bf16_t* Wq_hi = (bf16_t*)(kf + 737280);              // 384*256 bf16 each
  bf16_t* Wq_lo = Wq_hi + 98304;
  bf16_t* Wk_hi = Wq_lo + 98304;
  bf16_t* Wk_lo = Wk_hi + 98304;
  bf16_t* Wv_hi = Wk_lo + 98304;
  bf16_t* Wv_lo = Wv_hi + 98304;
  bf16_t* Wo_hi = Wv_lo + 98304;                       // 256*384
  bf16_t* Wo_lo = Wo_hi + 98304;
  bf16_t* Bt_hi = Wo_lo + 98304;                       // 256*256
  bf16_t* Bt_lo = Bt_hi + 65536;
  float* stats  = (float*)(Bt_lo + 65536);             // 384 fl

  k_zero<<<1, 384, 0, stream>>>(stats);
  k_s0<<<kN, 64, 0, stream>>>(tok_emb, Wf, s0);
  k_h0<<<(65536 * 64) / 256, 256, 0, stream>>>(x, wv, s0, h);

  for (int l = 0; l < 3; ++l) {
    const float* Wq   = (const float*)d_in[5 + 9 * l + 0];
    const float* Wk   = (const float*)d_in[5 + 9 * l + 1];
    const float* Wv   = (const float*)d_in[5 + 9 * l + 2];
    const float* filt = (const float*)d_in[5 + 9 * l + 3];
    const float* Wo   = (const float*)d_in[5 + 9 * l + 4];
    const float* Wm0  = (const float*)d_in[5 + 9 * l + 5];
    const float* Wm1  = (const float*)d_in[5 + 9 * l + 6];
    const float* g0   = (const float*)d_in[5 + 9 * l + 7];
    const float* g1   = (const float*)d_in[5 + 9 * l + 8];
    const int H = (l == 2) ? 160 : 360;
    const int S = H;                                   // Aq row stride (mult of 8)
    const int gy = (H + 63) / 64;                      // 6 or 3
    const int Kpad = gy * 64;                          // 384 or 192... (l==2: 192>160 ok, zero W)
    float* st = stats + l * 128;

    k_wqkv<<<384, 256, 0, stream>>>(Wq, Wk, Wv, H, Wq_hi, Wq_lo, Wk_hi, Wk_lo, Wv_hi, Wv_lo);
    k_wo<<<256, 384, 0, stream>>>(Wo, H, Wo_hi, Wo_lo);
    k_bt<<<256, 256, 0, stream>>>(Wm0, Wm1, Bt_hi, Bt_lo);
    k_kf<<<H, 256, 0, stream>>>(filt, H, (float2*)kf);
    k_qkv<<<dim3(gy, 1024), 256, 0, stream>>>(h, Wq_hi, Wq_lo, Wk_hi, Wk_lo, Wv_hi, Wv_lo,
                                              H, S, Aq, kvt);
    k_conv<<<64 * H, 256, 0, stream>>>(kvt, (const float2*)kf, H);
    k_tq<<<dim3(16, gy, 64), 256, 0, stream>>>(kvt, Aq, H, S);
    k_mix<<<dim3(4, 1024), 256, 0, stream>>>(Aq, S, Kpad, Wo_hi, Wo_lo, h);
    k_reg<<<dim3(4, 1024), 256, 0, stream>>>(h, Bt_hi, Bt_lo, y, st);
    k_bnact<<<(65536 * 64) / 256, 256, 0, stream>>>(y, st, g0, g1, h);
  }

  k_pool<<<64, 256, 0, stream>>>(h, w_out, (float*)d_out);
}

// Round 5
// 2534.937 us; speedup vs baseline: 1.9347x; 1.9347x over previous
//
#include <hip/hip_runtime.h>
#include <math.h>

namespace {

typedef __bf16 bf16_t;
typedef bf16_t bf16x8 __attribute__((ext_vector_type(8)));
typedef float floatx4 __attribute__((ext_vector_type(4)));

constexpr int kN = 1024;      // tokens
constexpr int kM = 64;        // multiplicity
constexpr int kP = 64;        // PE dim
constexpr int kD = 256;       // 4*M
constexpr float kEps = 1e-5f;
constexpr int kFN = 1024;     // FFT length

__device__ __forceinline__ float sigmoidf(float v) { return 1.0f / (1.0f + expf(-v)); }

__device__ __forceinline__ floatx4 mfma16(bf16x8 a, bf16x8 b, floatx4 c) {
  return __builtin_amdgcn_mfma_f32_16x16x32_bf16(a, b, c, 0, 0, 0);
}

// 3-term split product: acc += (ah+al)*(bh+bl) dropping al*bl
__device__ __forceinline__ void fma3(floatx4& acc, bf16x8 ah, bf16x8 al,
                                     bf16x8 bh, bf16x8 bl) {
  acc = mfma16(ah, bh, acc);
  acc = mfma16(ah, bl, acc);
  acc = mfma16(al, bh, acc);
}

// load 8 contiguous fp32 (global or LDS), split into hi/lo bf16 fragments
__device__ __forceinline__ void load_split8(const float* p, bf16x8& hi, bf16x8& lo) {
  const float4 u = *(const float4*)p;
  const float4 v = *(const float4*)(p + 4);
  const float a[8] = {u.x, u.y, u.z, u.w, v.x, v.y, v.z, v.w};
#pragma unroll
  for (int i = 0; i < 8; ++i) {
    const bf16_t h_ = (bf16_t)a[i];
    hi[i] = h_;
    lo[i] = (bf16_t)(a[i] - (float)h_);
  }
}

// ---------------------------------------------------------------- init
// s0[n, m] = sum_p (pe[n,p] + tok_emb[tt[n],p]) * Wf[p,m]
__global__ void k_s0(const float* __restrict__ tok_emb, const float* __restrict__ Wf,
                     float* __restrict__ s0) {
  __shared__ float f[kP];
  const int n = blockIdx.x;
  const int t = threadIdx.x;                       // 64 threads
  const int tt = (n == kN - 1) ? 2 : (n & 1);
  const int j = t >> 1;
  const float cexp = (float)(-9.210340371976184 / 64.0);   // -ln(10000)/P
  const float divj = expf((float)(2 * j) * cexp);
  const float ang = (float)n * divj;
  const float pe = (t & 1) ? cosf(ang) : sinf(ang);
  f[t] = pe + tok_emb[tt * kP + t];
  __syncthreads();
  float acc = 0.0f;
#pragma unroll 8
  for (int p = 0; p < kP; ++p) acc = fmaf(f[p], Wf[p * kM + t], acc);
  s0[n * kM + t] = acc;
}

// h[r, m, 0..3] = (s0[n,m], x[r]*wv[m])
__global__ void k_h0(const float* __restrict__ x, const float* __restrict__ wv,
                     const float* __restrict__ s0, float* __restrict__ h) {
  const int idx = blockIdx.x * 256 + threadIdx.x;  // r*64 + m
  const int r = idx >> 6;
  const int m = idx & 63;
  const int n = r & (kN - 1);
  const float w = wv[m];
  float4 o;
  o.x = s0[n * kM + m];
  o.y = x[r * 3 + 0] * w;
  o.z = x[r * 3 + 1] * w;
  o.w = x[r * 3 + 2] * w;
  ((float4*)h)[idx] = o;
}

// ---------------------------------------------------------------- weight prep (hi/lo planes)
__global__ void k_wqkv(const float* __restrict__ Wq, const float* __restrict__ Wk,
                       const float* __restrict__ Wv, int H,
                       bf16_t* __restrict__ Wq_hi, bf16_t* __restrict__ Wq_lo,
                       bf16_t* __restrict__ Wk_hi, bf16_t* __restrict__ Wk_lo,
                       bf16_t* __restrict__ Wv_hi, bf16_t* __restrict__ Wv_lo) {
  const int c = blockIdx.x;    // 0..383
  const int k = threadIdx.x;   // 0..255
  const bool ok = c < H;
  const float wq = ok ? Wq[k * H + c] : 0.f;
  const float wk = ok ? Wk[k * H + c] : 0.f;
  const float wv = ok ? Wv[k * H + c] : 0.f;
  const bf16_t qh = (bf16_t)wq, kh = (bf16_t)wk, vh = (bf16_t)wv;
  Wq_hi[c * 256 + k] = qh; Wq_lo[c * 256 + k] = (bf16_t)(wq - (float)qh);
  Wk_hi[c * 256 + k] = kh; Wk_lo[c * 256 + k] = (bf16_t)(wk - (float)kh);
  Wv_hi[c * 256 + k] = vh; Wv_lo[c * 256 + k] = (bf16_t)(wv - (float)vh);
}

__global__ void k_wo(const float* __restrict__ Wo, int H,
                     bf16_t* __restrict__ Wo_hi, bf16_t* __restrict__ Wo_lo) {
  const int d = blockIdx.x;    // 0..255
  const int c = threadIdx.x;   // 0..383
  const float w = (c < H) ? Wo[c * 256 + d] : 0.f;
  const bf16_t hi = (bf16_t)w;
  Wo_hi[d * 384 + c] = hi;
  Wo_lo[d * 384 + c] = (bf16_t)(w - (float)hi);
}

// block-diagonal expanded reg_linear weight, transposed: Bt[col][row]
__global__ void k_bt(const float* __restrict__ W0, const float* __restrict__ W1,
                     bf16_t* __restrict__ Bt_hi, bf16_t* __restrict__ Bt_lo) {
  const int col = blockIdx.x, row = threadIdx.x;
  const int k = col >> 2, ck = col & 3, m = row >> 2, cm = row & 3;
  float v = 0.f;
  if (cm == ck) v = (ck == 0 ? W0 : W1)[m * 64 + k];
  const bf16_t hi = (bf16_t)v;
  Bt_hi[col * 256 + row] = hi;
  Bt_lo[col * 256 + row] = (bf16_t)(v - (float)hi);
}

// ---------------------------------------------------------------- FFT (radix-2, no bit-reversal)
__device__ void fft_build_tw(float2* tw) {
  for (int j = threadIdx.x; j < kFN / 2; j += 256) {
    float s, c;
    sincosf(-6.283185307179586f * (float)j / (float)kFN, &s, &c);
    tw[j].x = c; tw[j].y = s;
  }
}

// forward DIF: natural in -> bit-reversed out
__device__ void fft_dif(float2* z, const float2* tw) {
  for (int span = kFN / 2; span >= 1; span >>= 1) {
    const int tm = (kFN / 2) / span;
    __syncthreads();
#pragma unroll
    for (int it = 0; it < 2; ++it) {
      const int p = threadIdx.x + it * 256;
      const int k = p & (span - 1);
      const int i = ((p & ~(span - 1)) << 1) | k;
      const float2 u = z[i];
      const float2 v = z[i + span];
      const float2 w = tw[k * tm];
      float2 sum, d, o;
      sum.x = u.x + v.x; sum.y = u.y + v.y;
      d.x = u.x - v.x;   d.y = u.y - v.y;
      o.x = d.x * w.x - d.y * w.y;
      o.y = d.x * w.y + d.y * w.x;
      z[i] = sum;
      z[i + span] = o;
    }
  }
}

// inverse DIT: bit-reversed in -> natural out (caller scales by 1/N)
__device__ void fft_dit_inv(float2* z, const float2* tw) {
  for (int span = 1; span <= kFN / 2; span <<= 1) {
    const int tm = (kFN / 2) / span;
    __syncthreads();
#pragma unroll
    for (int it = 0; it < 2; ++it) {
      const int p = threadIdx.x + it * 256;
      const int k = p & (span - 1);
      const int i = ((p & ~(span - 1)) << 1) | k;
      const float2 w = tw[k * tm];         // conj used below
      const float2 v = z[i + span];
      float2 tv, a, bq;
      tv.x = v.x * w.x + v.y * w.y;
      tv.y = v.y * w.x - v.x * w.y;
      const float2 u = z[i];
      a.x = u.x + tv.x;  a.y = u.y + tv.y;
      bq.x = u.x - tv.x; bq.y = u.y - tv.y;
      z[i] = a;
      z[i + span] = bq;
    }
  }
}

// filter spectrum, stored in DIF (bit-reversed) order; one block per channel
__global__ __launch_bounds__(256) void k_kf(const float* __restrict__ filt, int H,
                                            float2* __restrict__ kf) {
  __shared__ float2 z[kFN];
  __shared__ float2 tw[kFN / 2];
  const int c = blockIdx.x;
  fft_build_tw(tw);
  for (int n = threadIdx.x; n < kFN; n += 256) {
    z[n].x = filt[n * H + c];
    z[n].y = 0.0f;
  }
  fft_dif(z, tw);
  __syncthreads();
  for (int j = threadIdx.x; j < kFN; j += 256) kf[c * kFN + j] = z[j];
}

// circular conv in-place on kv_t rows; one block per (b, c)
__global__ __launch_bounds__(256) void k_conv(float* kvt, const float2* __restrict__ kf, int H) {
  __shared__ float2 z[kFN];
  __shared__ float2 tw[kFN / 2];
  const int row = blockIdx.x;              // b*H + c
  const int c = row % H;
  float* sig = kvt + (size_t)row * kFN;
  fft_build_tw(tw);
  for (int n = threadIdx.x; n < kFN; n += 256) {
    z[n].x = sig[n];
    z[n].y = 0.0f;
  }
  fft_dif(z, tw);
  __syncthreads();
  for (int j = threadIdx.x; j < kFN; j += 256) {
    const float2 a = z[j];
    const float2 b = kf[c * kFN + j];
    float2 o;
    o.x = a.x * b.x - a.y * b.y;
    o.y = a.x * b.y + a.y * b.x;
    z[j] = o;
  }
  fft_dit_inv(z, tw);
  __syncthreads();
  const float s = 1.0f / (float)kFN;
  for (int n = threadIdx.x; n < kFN; n += 256) sig[n] = z[n].x * s;
}

// ---------------------------------------------------------------- GEMM 1 (split MFMA): q/k/v
// qt[b*H+c][n] fp32 = h@Wq ; kvt[b*H+c][n] fp32 = (h@Wk)*(h@Wv)
__global__ __launch_bounds__(256) void k_qkv(const float* __restrict__ h,
    const bf16_t* __restrict__ Wq_hi, const bf16_t* __restrict__ Wq_lo,
    const bf16_t* __restrict__ Wk_hi, const bf16_t* __restrict__ Wk_lo,
    const bf16_t* __restrict__ Wv_hi, const bf16_t* __restrict__ Wv_lo,
    int H, float* __restrict__ qt, float* __restrict__ kvt) {
  const int t = threadIdx.x;
  const int lane = t & 63, wave = t >> 6;
  const int l15 = lane & 15, quad = lane >> 4;
  const int c0 = blockIdx.x * 64;          // output channels (fast dim -> L2 reuse of h)
  const int r0 = blockIdx.y * 64;          // flattened token rows
  const int wr = (wave & 1) * 32, wc = (wave >> 1) * 32;
  floatx4 aq[2][2] = {}, ak_[2][2] = {}, av_[2][2] = {};
  const float* Ap = h + (size_t)(r0 + wr + l15) * 256 + quad * 8;
  const size_t boff = (size_t)(c0 + wc + l15) * 256 + quad * 8;
  for (int kk = 0; kk < 256; kk += 32) {
    bf16x8 ah0, al0, ah1, al1;
    load_split8(Ap + kk, ah0, al0);
    load_split8(Ap + 16 * 256 + kk, ah1, al1);
    {
      const bf16x8 bh0 = *(const bf16x8*)(Wq_hi + boff + kk);
      const bf16x8 bh1 = *(const bf16x8*)(Wq_hi + boff + 16 * 256 + kk);
      const bf16x8 bl0 = *(const bf16x8*)(Wq_lo + boff + kk);
      const bf16x8 bl1 = *(const bf16x8*)(Wq_lo + boff + 16 * 256 + kk);
      fma3(aq[0][0], ah0, al0, bh0, bl0); fma3(aq[0][1], ah0, al0, bh1, bl1);
      fma3(aq[1][0], ah1, al1, bh0, bl0); fma3(aq[1][1], ah1, al1, bh1, bl1);
    }
    {
      const bf16x8 bh0 = *(const bf16x8*)(Wk_hi + boff + kk);
      const bf16x8 bh1 = *(const bf16x8*)(Wk_hi + boff + 16 * 256 + kk);
      const bf16x8 bl0 = *(const bf16x8*)(Wk_lo + boff + kk);
      const bf16x8 bl1 = *(const bf16x8*)(Wk_lo + boff + 16 * 256 + kk);
      fma3(ak_[0][0], ah0, al0, bh0, bl0); fma3(ak_[0][1], ah0, al0, bh1, bl1);
      fma3(ak_[1][0], ah1, al1, bh0, bl0); fma3(ak_[1][1], ah1, al1, bh1, bl1);
    }
    {
      const bf16x8 bh0 = *(const bf16x8*)(Wv_hi + boff + kk);
      const bf16x8 bh1 = *(const bf16x8*)(Wv_hi + boff + 16 * 256 + kk);
      const bf16x8 bl0 = *(const bf16x8*)(Wv_lo + boff + kk);
      const bf16x8 bl1 = *(const bf16x8*)(Wv_lo + boff + 16 * 256 + kk);
      fma3(av_[0][0], ah0, al0, bh0, bl0); fma3(av_[0][1], ah0, al0, bh1, bl1);
      fma3(av_[1][0], ah1, al1, bh0, bl0); fma3(av_[1][1], ah1, al1, bh1, bl1);
    }
  }
  const int b = r0 >> 10;
  const int n0 = r0 & 1023;
#pragma unroll
  for (int j = 0; j < 2; ++j) {
    const int c = c0 + wc + j * 16 + l15;
    if (c < H) {
      const size_t rb = (((size_t)(b * H + c)) << 10) + n0 + wr + quad * 4;
      // q -> qt[c][n], float4 along n (same layout as kv)
#pragma unroll
      for (int i = 0; i < 2; ++i) {
        float4 p;
        p.x = aq[i][j][0]; p.y = aq[i][j][1];
        p.z = aq[i][j][2]; p.w = aq[i][j][3];
        *(float4*)(qt + rb + i * 16) = p;
      }
      // kv -> kvt[c][n]
#pragma unroll
      for (int i = 0; i < 2; ++i) {
        float4 p;
        p.x = ak_[i][j][0] * av_[i][j][0];
        p.y = ak_[i][j][1] * av_[i][j][1];
        p.z = ak_[i][j][2] * av_[i][j][2];
        p.w = ak_[i][j][3] * av_[i][j][3];
        *(float4*)(kvt + rb + i * 16) = p;
      }
    }
  }
}

// ---------------------------------------------------------------- GEMM 2 (split MFMA): h += (q*conv) @ Wo
// A = qt*kvt (c-major), staged+transposed through LDS per 32-wide K chunk
__global__ __launch_bounds__(256) void k_mix(const float* __restrict__ qt,
    const float* __restrict__ kvt, int H, int KT,
    const bf16_t* __restrict__ Wo_hi, const bf16_t* __restrict__ Wo_lo,
    float* __restrict__ h) {
  __shared__ float smem[4352];             // As: 64 n x 36 (2304) ; epilogue: 64 x 68
  const int t = threadIdx.x;
  const int lane = t & 63, wave = t >> 6;
  const int l15 = lane & 15, quad = lane >> 4;
  const int d0 = blockIdx.x * 64, r0 = blockIdx.y * 64;
  const int b = r0 >> 10, n0 = r0 & 1023;
  const int wr = (wave & 1) * 32, wc = (wave >> 1) * 32;
  floatx4 acc[2][2] = {};
  const int cl = t >> 3, n8 = (t & 7) * 8;
  const size_t boff = (size_t)(d0 + wc + l15) * 384 + quad * 8;
  for (int kt = 0; kt < KT; ++kt) {
    const int ck0 = kt * 32;
    __syncthreads();
    {
      const int c = ck0 + cl;
      float p[8] = {};
      if (c < H) {
        const size_t o = (((size_t)(b * H + c)) << 10) + n0 + n8;
        const float4 q0 = *(const float4*)(qt + o);
        const float4 q1 = *(const float4*)(qt + o + 4);
        const float4 v0 = *(const float4*)(kvt + o);
        const float4 v1 = *(const float4*)(kvt + o + 4);
        p[0] = q0.x * v0.x; p[1] = q0.y * v0.y; p[2] = q0.z * v0.z; p[3] = q0.w * v0.w;
        p[4] = q1.x * v1.x; p[5] = q1.y * v1.y; p[6] = q1.z * v1.z; p[7] = q1.w * v1.w;
      }
#pragma unroll
      for (int u = 0; u < 8; ++u) smem[(n8 + u) * 36 + cl] = p[u];
    }
    __syncthreads();
    bf16x8 ah0, al0, ah1, al1;
    load_split8(smem + (wr + l15) * 36 + quad * 8, ah0, al0);
    load_split8(smem + (wr + 16 + l15) * 36 + quad * 8, ah1, al1);
    const bf16x8 bh0 = *(const bf16x8*)(Wo_hi + boff + ck0);
    const bf16x8 bh1 = *(const bf16x8*)(Wo_hi + boff + 16 * 384 + ck0);
    const bf16x8 bl0 = *(const bf16x8*)(Wo_lo + boff + ck0);
    const bf16x8 bl1 = *(const bf16x8*)(Wo_lo + boff + 16 * 384 + ck0);
    fma3(acc[0][0], ah0, al0, bh0, bl0); fma3(acc[0][1], ah0, al0, bh1, bl1);
    fma3(acc[1][0], ah1, al1, bh0, bl0); fma3(acc[1][1], ah1, al1, bh1, bl1);
  }
  __syncthreads();
#pragma unroll
  for (int i = 0; i < 2; ++i)
#pragma unroll
    for (int j = 0; j < 2; ++j)
#pragma unroll
      for (int r = 0; r < 4; ++r)
        smem[(wr + i * 16 + quad * 4 + r) * 68 + wc + j * 16 + l15] = acc[i][j][r];
  __syncthreads();
  const int nl = t >> 2, q4 = t & 3;
  const size_t gi = (size_t)(r0 + nl) * 256 + d0 + q4 * 16;
#pragma unroll
  for (int u = 0; u < 4; ++u) {
    float4 hv = *(const float4*)(h + gi + u * 4);
    hv.x += smem[nl * 68 + q4 * 16 + u * 4 + 0];
    hv.y += smem[nl * 68 + q4 * 16 + u * 4 + 1];
    hv.z += smem[nl * 68 + q4 * 16 + u * 4 + 2];
    hv.w += smem[nl * 68 + q4 * 16 + u * 4 + 3];
    *(float4*)(h + gi + u * 4) = hv;
  }
}

// ---------------------------------------------------------------- GEMM 3 (split MFMA): reg_linear + BN partials
__global__ __launch_bounds__(256) void k_reg(const float* __restrict__ h,
    const bf16_t* __restrict__ Bt_hi, const bf16_t* __restrict__ Bt_lo,
    float* __restrict__ y, float* __restrict__ partial) {
  __shared__ float smem[4352];             // As: 64 x 36 ; epilogue: 64 x 68
  __shared__ float red[128];
  const int t = threadIdx.x;
  const int lane = t & 63, wave = t >> 6;
  const int l15 = lane & 15, quad = lane >> 4;
  const int c0 = blockIdx.x * 64, r0 = blockIdx.y * 64;
  const int wr = (wave & 1) * 32, wc = (wave >> 1) * 32;
  floatx4 acc[2][2] = {};
  const int rl = t >> 2, o8 = (t & 3) * 8;
  const size_t boff = (size_t)(c0 + wc + l15) * 256 + quad * 8;
  for (int kt = 0; kt < 8; ++kt) {
    const int kk = kt * 32;
    __syncthreads();
    {
      const float* src = h + (size_t)(r0 + rl) * 256 + kk + o8;
      float* dst = smem + rl * 36 + o8;
      *(float4*)dst = *(const float4*)src;
      *(float4*)(dst + 4) = *(const float4*)(src + 4);
    }
    __syncthreads();
    bf16x8 ah0, al0, ah1, al1;
    load_split8(smem + (wr + l15) * 36 + quad * 8, ah0, al0);
    load_split8(smem + (wr + 16 + l15) * 36 + quad * 8, ah1, al1);
    const bf16x8 bh0 = *(const bf16x8*)(Bt_hi + boff + kk);
    const bf16x8 bh1 = *(const bf16x8*)(Bt_hi + boff + 16 * 256 + kk);
    const bf16x8 bl0 = *(const bf16x8*)(Bt_lo + boff + kk);
    const bf16x8 bl1 = *(const bf16x8*)(Bt_lo + boff + 16 * 256 + kk);
    fma3(acc[0][0], ah0, al0, bh0, bl0); fma3(acc[0][1], ah0, al0, bh1, bl1);
    fma3(acc[1][0], ah1, al1, bh0, bl0); fma3(acc[1][1], ah1, al1, bh1, bl1);
  }
  // per-column sum of squares (lane holds one column per j)
#pragma unroll
  for (int j = 0; j < 2; ++j) {
    float s = 0.f;
#pragma unroll
    for (int i = 0; i < 2; ++i)
#pragma unroll
      for (int r = 0; r < 4; ++r)
        s = fmaf(acc[i][j][r], acc[i][j][r], s);
    s += __shfl_down(s, 32);
    s += __shfl_down(s, 16);
    if (lane < 16) red[wave * 32 + j * 16 + lane] = s;
  }
  __syncthreads();
#pragma unroll
  for (int i = 0; i < 2; ++i)
#pragma unroll
    for (int j = 0; j < 2; ++j)
#pragma unroll
      for (int r = 0; r < 4; ++r)
        smem[(wr + i * 16 + quad * 4 + r) * 68 + wc + j * 16 + l15] = acc[i][j][r];
  __syncthreads();
  const int nl = t >> 2, q4 = t & 3;
  const size_t gi = (size_t)(r0 + nl) * 256 + c0 + q4 * 16;
#pragma unroll
  for (int u = 0; u < 4; ++u) {
    float4 yv;
    yv.x = smem[nl * 68 + q4 * 16 + u * 4 + 0];
    yv.y = smem[nl * 68 + q4 * 16 + u * 4 + 1];
    yv.z = smem[nl * 68 + q4 * 16 + u * 4 + 2];
    yv.w = smem[nl * 68 + q4 * 16 + u * 4 + 3];
    *(float4*)(y + gi + u * 4) = yv;
  }
  if (t < 64) {
    const int w0 = (t >= 32) ? 2 : 0;
    const float v = red[w0 * 32 + (t & 31)] + red[(w0 + 1) * 32 + (t & 31)];
    // one slot per column: race-free by construction; component combine in k_stat
    partial[(size_t)blockIdx.y * 256 + c0 + t] = v;
  }
}

// reduce partials over 1024 r-blocks -> stats[128] (s-norms [0,64), v-norms [64,128))
__global__ __launch_bounds__(1024) void k_stat(const float* __restrict__ partial,
                                               float* __restrict__ st) {
  __shared__ float acc[4][256];
  __shared__ float tot[256];
  const int t = threadIdx.x;
  const int slot = t & 255, g = t >> 8;
  float s = 0.f;
  for (int r = g; r < 1024; r += 4) s += partial[(size_t)r * 256 + slot];
  acc[g][slot] = s;
  __syncthreads();
  if (t < 256) tot[t] = acc[0][t] + acc[1][t] + acc[2][t] + acc[3][t];
  __syncthreads();
  if (t < 64) {
    st[t] = tot[4 * t];                                   // scalar channel m
    st[64 + t] = tot[4 * t + 1] + tot[4 * t + 2] + tot[4 * t + 3];  // |v|^2 over 3 comps
  }
}

// ---------------------------------------------------------------- BN + norm-activation + residual
__global__ void k_bnact(const float* __restrict__ y, const float* __restrict__ stats,
    const float* __restrict__ g0, const float* __restrict__ g1, float* __restrict__ h) {
  const int idx = blockIdx.x * 256 + threadIdx.x;  // r*64 + m
  const int m = idx & 63;
  const float inv0 = g0[m] / sqrtf(stats[m] * (1.0f / 65536.0f) + kEps);
  const float inv1 = g1[m] / sqrtf(stats[64 + m] * (1.0f / 65536.0f) + kEps);
  const float4 v = ((const float4*)y)[idx];
  const float s = v.x * inv0;
  const float vx = v.y * inv1, vy = v.z * inv1, vz = v.w * inv1;
  const float so = s * sigmoidf(fabsf(s));
  const float vn = sqrtf(fmaf(vx, vx, fmaf(vy, vy, vz * vz)) + kEps);
  const float gv = sigmoidf(vn);
  float4 hv = ((float4*)h)[idx];
  hv.x += so;
  hv.y += vx * gv; hv.z += vy * gv; hv.w += vz * gv;
  ((float4*)h)[idx] = hv;
}

// ---------------------------------------------------------------- mean-pool + einsum
__global__ __launch_bounds__(256) void k_pool(const float* __restrict__ h,
    const float* __restrict__ w_out, float* __restrict__ out) {
  __shared__ float r0s[256], r1s[256], r2s[256];
  const int b = blockIdx.x;
  const int t = threadIdx.x;
  float p0 = 0, p1 = 0, p2 = 0;
  for (int idx = t; idx < kN * kM; idx += 256) {
    const int m = idx & 63;
    const float4 v = ((const float4*)h)[(size_t)b * (kN * kM) + idx];
    const float w = w_out[m];
    p0 = fmaf(v.y, w, p0);
    p1 = fmaf(v.z, w, p1);
    p2 = fmaf(v.w, w, p2);
  }
  r0s[t] = p0; r1s[t] = p1; r2s[t] = p2;
  __syncthreads();
  for (int s = 128; s > 0; s >>= 1) {
    if (t < s) { r0s[t] += r0s[t + s]; r1s[t] += r1s[t + s]; r2s[t] += r2s[t + s]; }
    __syncthreads();
  }
  if (t == 0) {
    out[b * 3 + 0] = r0s[0] * (1.0f / kN);
    out[b * 3 + 1] = r1s[0] * (1.0f / kN);
    out[b * 3 + 2] = r2s[0] * (1.0f / kN);
  }
}

} // namespace

extern "C" void kernel_launch(void* const* d_in, const int* in_sizes, int n_in,
                              void* d_out, int out_size, void* d_ws, size_t ws_size,
                              hipStream_t stream) {
  const float* x       = (const float*)d_in[0];
  const float* tok_emb = (const float*)d_in[1];
  const float* Wf      = (const float*)d_in[2];
  const float* wv      = (const float*)d_in[3];
  const float* w_out   = (const float*)d_in[4];

  float* ws    = (float*)d_ws;
  float*  h    = ws;                                   // 16,777,216 fl
  float*  kvt  = ws + 16777216;                        // 23,592,960 fl
  float*  qt   = kvt + 23592960;                       // 23,592,960 fl
  float*  y    = qt;                                   // alias: qt dead once k_mix done
  float*  partial = qt + 20000000;                     // 262,144 fl inside qt region, past y end
  float*  s0   = qt + 23592960;                        //     65,536 fl
  float*  kf   = s0 + 65536;                           //    737,280 fl
  bf16_t* Wq_hi = (bf16_t*)(kf + 737280);              // 384*256 bf16 each
  bf16_t* Wq_lo = Wq_hi + 98304;
  bf16_t* Wk_hi = Wq_lo + 98304;
  bf16_t* Wk_lo = Wk_hi + 98304;
  bf16_t* Wv_hi = Wk_lo + 98304;
  bf16_t* Wv_lo = Wv_hi + 98304;
  bf16_t* Wo_hi = Wv_lo + 98304;                       // 256*384
  bf16_t* Wo_lo = Wo_hi + 98304;
  bf16_t* Bt_hi = Wo_lo + 98304;                       // 256*256
  bf16_t* Bt_lo = Bt_hi + 65536;
  float* stats  = (float*)(Bt_lo + 65536);             // 384 fl

  k_s0<<<kN, 64, 0, stream>>>(tok_emb, Wf, s0);
  k_h0<<<(65536 * 64) / 256, 256, 0, stream>>>(x, wv, s0, h);

  for (int l = 0; l < 3; ++l) {
    const float* Wq   = (const float*)d_in[5 + 9 * l + 0];
    const float* Wk   = (const float*)d_in[5 + 9 * l + 1];
    const float* Wv   = (const float*)d_in[5 + 9 * l + 2];
    const float* filt = (const float*)d_in[5 + 9 * l + 3];
    const float* Wo   = (const float*)d_in[5 + 9 * l + 4];
    const float* Wm0  = (const float*)d_in[5 + 9 * l + 5];
    const float* Wm1  = (const float*)d_in[5 + 9 * l + 6];
    const float* g0   = (const float*)d_in[5 + 9 * l + 7];
    const float* g1   = (const float*)d_in[5 + 9 * l + 8];
    const int H = (l == 2) ? 160 : 360;
    const int gy = (H + 63) / 64;                      // 6 or 3
    const int KT = gy * 2;                             // K chunks of 32 (384 or 192, zero-padded)
    float* st = stats + l * 128;

    k_wqkv<<<384, 256, 0, stream>>>(Wq, Wk, Wv, H, Wq_hi, Wq_lo, Wk_hi, Wk_lo, Wv_hi, Wv_lo);
    k_wo<<<256, 384, 0, stream>>>(Wo, H, Wo_hi, Wo_lo);
    k_bt<<<256, 256, 0, stream>>>(Wm0, Wm1, Bt_hi, Bt_lo);
    k_kf<<<H, 256, 0, stream>>>(filt, H, (float2*)kf);
    k_qkv<<<dim3(gy, 1024), 256, 0, stream>>>(h, Wq_hi, Wq_lo, Wk_hi, Wk_lo, Wv_hi, Wv_lo,
                                              H, qt, kvt);
    k_conv<<<64 * H, 256, 0, stream>>>(kvt, (const float2*)kf, H);
    k_mix<<<dim3(4, 1024), 256, 0, stream>>>(qt, kvt, H, KT, Wo_hi, Wo_lo, h);
    k_reg<<<dim3(4, 1024), 256, 0, stream>>>(h, Bt_hi, Bt_lo, y, partial);
    k_stat<<<1, 1024, 0, stream>>>(partial, st);
    k_bnact<<<(65536 * 64) / 256, 256, 0, stream>>>(y, st, g0, g1, h);
  }

  k_pool<<<64, 256, 0, stream>>>(h, w_out, (float*)d_out);
}